// Round 5
// baseline (179.307 us; speedup 1.0000x reference)
//
#include <hip/hip_runtime.h>
#include <hip/hip_bf16.h>

#define NA   312      // attributes
#define LAT  64       // latent per attribute (K)
#define HID  128      // hidden per attribute (N)
#define NB   8192     // batch
#define MB   256      // rows per block
#define NBT  (NB / MB)   // 32 batch tiles
#define MT   4           // 16-row tiles per wave (4 waves * 64 rows = 256)

typedef __attribute__((ext_vector_type(8))) short bf16x8;
typedef __attribute__((ext_vector_type(4))) float f32x4;

// fp32 -> bf16 RNE scalar (prep kernel only; main path uses packed casts)
__device__ inline short f2bf(float f) {
    unsigned u = __builtin_bit_cast(unsigned, f);
    u += 0x7FFFu + ((u >> 16) & 1u);
    return (short)(u >> 16);
}

// 8x fp32 -> bf16x8; __float22bfloat162_rn lowers to v_cvt_pk_bf16_f32.
// memcpy (not bit_cast): __hip_bfloat162 is not trivially copyable; the
// copy folds to register moves.
__device__ inline bf16x8 pack8(float4 v0, float4 v1) {
    __hip_bfloat162 c[4] = {
        __float22bfloat162_rn(float2{v0.x, v0.y}),
        __float22bfloat162_rn(float2{v0.z, v0.w}),
        __float22bfloat162_rn(float2{v1.x, v1.y}),
        __float22bfloat162_rn(float2{v1.z, v1.w})};
    bf16x8 f;
    __builtin_memcpy(&f, &c[0], 16);
    return f;
}

// ---------------- prep: W1 [A][LAT][HID] fp32 -> frag-ordered bf16 ----------
// frag entry e = (nt*2+kk)*64 + lane holds 8 bf16:
//   element j = W1[a][ kk*32 + (lane>>4)*8 + j ][ nt*16 + (lane&15) ]
__global__ __launch_bounds__(256, 2) void prep_w1(
    const float* __restrict__ W1, short* __restrict__ w1f)
{
    __shared__ float lds[LAT * HID];   // 32 KB fp32
    const int a   = blockIdx.x;
    const int tid = threadIdx.x;

    const float4* src = reinterpret_cast<const float4*>(W1 + (size_t)a * (LAT * HID));
    float4* ldsv = reinterpret_cast<float4*>(lds);
    #pragma unroll
    for (int i = 0; i < (LAT * HID / 4) / 256; ++i)     // 8 iters, coalesced
        ldsv[i * 256 + tid] = src[i * 256 + tid];
    __syncthreads();

    bf16x8* dst = reinterpret_cast<bf16x8*>(w1f + (size_t)a * (LAT * HID));
    #pragma unroll
    for (int i = 0; i < 4; ++i) {
        const int e    = i * 256 + tid;
        const int nt   = e >> 7;
        const int kk   = (e >> 6) & 1;
        const int lane = e & 63;
        const int n  = nt * 16 + (lane & 15);
        const int k0 = kk * 32 + (lane >> 4) * 8;
        bf16x8 f;
        #pragma unroll
        for (int j = 0; j < 8; ++j)
            f[j] = f2bf(lds[(k0 + j) * HID + n]);
        dst[e] = f;   // consecutive e across tid -> coalesced 16 B stores
    }
}

// ---------------- main: no LDS, no barrier ----------------------------------
// One block: attribute a, 256 rows, 4 waves x 64 rows. Layer 1 = bf16 MFMA
// (A built in-register from global x via packed cvt; B = frag-ordered w1f,
// coalesced, L1-resident). b1 folded into MFMA C-in. Layer 2 + sigmoid fp32.
__global__ __launch_bounds__(256, 2) void attr_decoder_main(
    const float* __restrict__ x,
    const short* __restrict__ w1f,
    const float* __restrict__ b1,
    const float* __restrict__ W2,
    const float* __restrict__ b2,
    float* __restrict__ out)
{
    const int tid  = threadIdx.x;
    const int a    = blockIdx.x >> 5;        // /NBT; 32 consecutive blocks share w1f[a]
    const int bt   = blockIdx.x & (NBT - 1); // XCD = bt%8 for all a -> out-line write merge
    const int w    = tid >> 6;
    const int lane = tid & 63;
    const int llo  = lane & 15;
    const int lhi  = lane >> 4;
    const int rowbase = bt * MB + w * 64;

    // ---- A fragments: x rows straight from global, packed fp32 -> bf16 ----
    bf16x8 afrag[MT][2];
    #pragma unroll
    for (int mt = 0; mt < MT; ++mt) {
        const float* xrow = x + (size_t)(rowbase + mt * 16 + llo) * (NA * LAT)
                              + (size_t)a * LAT;
        #pragma unroll
        for (int kk = 0; kk < 2; ++kk) {
            const float4* p = reinterpret_cast<const float4*>(xrow + kk * 32 + lhi * 8);
            afrag[mt][kk] = pack8(p[0], p[1]);
        }
    }

    // ---- layer 1 MFMA + fused layer-2 partials ----
    const bf16x8* wf = reinterpret_cast<const bf16x8*>(w1f + (size_t)a * (LAT * HID));
    const float*  b1a = b1 + a * HID;
    const float*  w2a = W2 + a * HID;   // W2 flat [A*HID]
    float p2[MT][4] = {};               // partial sums of relu(h)*w2
    #pragma unroll 4
    for (int nt = 0; nt < 8; ++nt) {
        const bf16x8 bf0 = wf[(nt * 2 + 0) * 64 + lane];   // coalesced 1 KB/instr
        const bf16x8 bf1 = wf[(nt * 2 + 1) * 64 + lane];
        const int n = nt * 16 + llo;
        const float b1v = b1a[n];
        const float w2v = w2a[n];
        const f32x4 cin = {b1v, b1v, b1v, b1v};   // D col = lane&15 -> same n all regs
        #pragma unroll
        for (int mt = 0; mt < MT; ++mt) {
            f32x4 acc = cin;
            acc = __builtin_amdgcn_mfma_f32_16x16x32_bf16(afrag[mt][0], bf0, acc, 0, 0, 0);
            acc = __builtin_amdgcn_mfma_f32_16x16x32_bf16(afrag[mt][1], bf1, acc, 0, 0, 0);
            #pragma unroll
            for (int r = 0; r < 4; ++r)
                p2[mt][r] = fmaf(fmaxf(acc[r], 0.f), w2v, p2[mt][r]);
        }
    }

    // ---- in-wave row reduction (over n-lanes), sigmoid, store ----
    const float ob = b2[a];
    #pragma unroll
    for (int mt = 0; mt < MT; ++mt) {
        #pragma unroll
        for (int r = 0; r < 4; ++r) {
            float s = p2[mt][r];
            s += __shfl_xor(s, 1);
            s += __shfl_xor(s, 2);
            s += __shfl_xor(s, 4);
            s += __shfl_xor(s, 8);
            s = 1.0f / (1.0f + __expf(-(s + ob)));   // hw v_exp_f32
            if (llo == 0) {
                const int row = rowbase + mt * 16 + lhi * 4 + r;
                out[(size_t)row * NA + a] = s;
            }
        }
    }
}

extern "C" void kernel_launch(void* const* d_in, const int* in_sizes, int n_in,
                              void* d_out, int out_size, void* d_ws, size_t ws_size,
                              hipStream_t stream) {
    const float* x  = (const float*)d_in[0];
    const float* W1 = (const float*)d_in[1];
    const float* b1 = (const float*)d_in[2];
    const float* W2 = (const float*)d_in[3];
    const float* b2 = (const float*)d_in[4];
    float* out = (float*)d_out;
    short* w1f = (short*)d_ws;          // 312*8192 bf16 = 5.1 MB (ws ~2.6 GB)

    hipLaunchKernelGGL(prep_w1, dim3(NA), dim3(256), 0, stream, W1, w1f);
    hipLaunchKernelGGL(attr_decoder_main, dim3(NA * NBT), dim3(256), 0, stream,
                       x, w1f, b1, W2, b2, out);
}